// Round 7
// baseline (85.818 us; speedup 1.0000x reference)
//
#include <hip/hip_runtime.h>

// d_ws layout: 3408 x uint2 (half4 each): lo = half2(cos,  sin) [X-dot]
//                                         hi = half2(-sin, cos) [Y-dot]
// (Y = s*wc - c*ws = dot2((c,s),(-ws,wc)) — swap-free form.)
// [0..15]     conv1 (o*4 + dy*2 + dx)
// [16..527]   conv2 (o*64 + c*16 + dy*4 + dx)
// [528..3407] ff    (f*10 + n)
#define WT_W1 0
#define WT_W2 16
#define WT_FF 528

typedef _Float16 h2 __attribute__((ext_vector_type(2)));

__device__ __forceinline__ float fdot2(unsigned a, unsigned b, float c) {
    return __builtin_amdgcn_fdot2(__builtin_bit_cast(h2, a),
                                  __builtin_bit_cast(h2, b), c, false);
}
__device__ __forceinline__ unsigned packh2(float x, float y) {
    h2 h; h.x = (_Float16)x; h.y = (_Float16)y;
    return __builtin_bit_cast(unsigned, h);
}

__global__ void ringnn_setup(const float* __restrict__ w1,
                             const float* __restrict__ w2,
                             const float* __restrict__ ffw,
                             uint2* __restrict__ wt) {
    int t = blockIdx.x * blockDim.x + threadIdx.x;
    if (t >= 3408) return;
    float a;
    if (t < 16)        a = w1[t];
    else if (t < 528)  a = w2[t - 16];
    else               a = ffw[t - 528];
    float s, c;
    __sincosf(a, &s, &c);
    uint2 v;
    v.x = packh2(c, s);     // X-dot operand
    v.y = packh2(-s, c);    // Y-dot operand
    wt[t] = v;
}

// BARRIER-FREE: 4 waves/block, each wave owns one image end-to-end.
// LDS is wave-private -> no __syncthreads anywhere (in-wave ds ordering is
// enforced by compiler lgkmcnt waits). Weights never touch LDS: stage 1/2
// addresses are wave-uniform (scalar s_load path), stage 3 is per-lane VMEM.
// NOTE: plain __launch_bounds__(256) — (256,8) caused catastrophic spill (R3).
__global__ __launch_bounds__(256) void ringnn_main(
    const float* __restrict__ x,
    const uint2* __restrict__ wt,
    float* __restrict__ out)
{
    __shared__ unsigned cs1[4][784];        // [wave][c*196 + i*14 + j], half2
    __shared__ unsigned cs2[4][288];        // [wave][(i*6+j)*8 + o], half2

    const int t    = threadIdx.x;
    const int wv   = t >> 6;                // wave = image slot
    const int lane = t & 63;
    const int b    = blockIdx.x * 4 + wv;
    const float* xb = x + b * 784;

    // ---- Stage 1: sincos from global + 2x2/s2 conv, 1->4 ch (one wave) ----
    for (int pos = lane; pos < 196; pos += 64) {
        const int i = pos / 14;
        const int j = pos - i * 14;
        const float* px = xb + (2 * i) * 28 + 2 * j;
        float2 p0 = *(const float2*)(px);
        float2 p1 = *(const float2*)(px + 28);
        float s0, c0, s1, c1, s2, c2, s3, c3;
        __sincosf(p0.x, &s0, &c0);
        __sincosf(p0.y, &s1, &c1);
        __sincosf(p1.x, &s2, &c2);
        __sincosf(p1.y, &s3, &c3);
        unsigned v0 = packh2(c0, s0), v1 = packh2(c1, s1);
        unsigned v2 = packh2(c2, s2), v3 = packh2(c3, s3);
        #pragma unroll
        for (int o = 0; o < 4; ++o) {
            uint2 wa = wt[WT_W1 + o * 4 + 0], wb = wt[WT_W1 + o * 4 + 1];
            uint2 wc = wt[WT_W1 + o * 4 + 2], wd = wt[WT_W1 + o * 4 + 3];
            float X = 0.f, Y = 0.f;
            X = fdot2(v0, wa.x, X); Y = fdot2(v0, wa.y, Y);
            X = fdot2(v1, wb.x, X); Y = fdot2(v1, wb.y, Y);
            X = fdot2(v2, wc.x, X); Y = fdot2(v2, wc.y, Y);
            X = fdot2(v3, wd.x, X); Y = fdot2(v3, wd.y, Y);
            float rinv = rsqrtf(fmaxf(fmaf(X, X, Y * Y), 1e-30f));
            cs1[wv][o * 196 + pos] = packh2(X * rinv, Y * rinv);
        }
    }

    // ---- Stage 2: 4x4/s2 conv, 4->8 ch, 14x14 -> 6x6 (one wave) ----
    // lane = output position (36 active); all 8 o accumulated in registers;
    // every weight address is wave-uniform -> scalar loads, zero LDS traffic.
    if (lane < 36) {
        const int i = lane / 6;
        const int j = lane - i * 6;
        const unsigned* cb = &cs1[wv][(2 * i) * 14 + 2 * j];
        float X0=0.f,X1=0.f,X2=0.f,X3=0.f,X4=0.f,X5=0.f,X6=0.f,X7=0.f;
        float Y0=0.f,Y1=0.f,Y2=0.f,Y3=0.f,Y4=0.f,Y5=0.f,Y6=0.f,Y7=0.f;
        #pragma unroll
        for (int c = 0; c < 4; ++c) {
            // register-cache the 16 activation taps for this channel
            uint2 a[4][2];
            #pragma unroll
            for (int dy = 0; dy < 4; ++dy) {
                const unsigned* r = cb + c * 196 + dy * 14;  // 8B aligned
                a[dy][0] = *(const uint2*)(r);
                a[dy][1] = *(const uint2*)(r + 2);
            }
            #pragma unroll
            for (int o = 0; o < 8; ++o) {
                float Xa = 0.f, Ya = 0.f;
                const uint2* wp = wt + WT_W2 + o * 64 + c * 16;
                #pragma unroll
                for (int dy = 0; dy < 4; ++dy) {
                    uint2 w0 = wp[dy * 4 + 0], w1_ = wp[dy * 4 + 1];
                    uint2 w2_ = wp[dy * 4 + 2], w3_ = wp[dy * 4 + 3];
                    Xa = fdot2(a[dy][0].x, w0.x, Xa); Ya = fdot2(a[dy][0].x, w0.y, Ya);
                    Xa = fdot2(a[dy][0].y, w1_.x, Xa); Ya = fdot2(a[dy][0].y, w1_.y, Ya);
                    Xa = fdot2(a[dy][1].x, w2_.x, Xa); Ya = fdot2(a[dy][1].x, w2_.y, Ya);
                    Xa = fdot2(a[dy][1].y, w3_.x, Xa); Ya = fdot2(a[dy][1].y, w3_.y, Ya);
                }
                switch (o) {
                    case 0: X0 += Xa; Y0 += Ya; break;
                    case 1: X1 += Xa; Y1 += Ya; break;
                    case 2: X2 += Xa; Y2 += Ya; break;
                    case 3: X3 += Xa; Y3 += Ya; break;
                    case 4: X4 += Xa; Y4 += Ya; break;
                    case 5: X5 += Xa; Y5 += Ya; break;
                    case 6: X6 += Xa; Y6 += Ya; break;
                    case 7: X7 += Xa; Y7 += Ya; break;
                }
            }
        }
        unsigned rr[8];
        {
            float Xs[8] = {X0,X1,X2,X3,X4,X5,X6,X7};
            float Ys[8] = {Y0,Y1,Y2,Y3,Y4,Y5,Y6,Y7};
            #pragma unroll
            for (int o = 0; o < 8; ++o) {
                float rv = rsqrtf(fmaxf(fmaf(Xs[o], Xs[o], Ys[o] * Ys[o]), 1e-30f));
                rr[o] = packh2(Xs[o] * rv, Ys[o] * rv);
            }
        }
        uint2* dst = (uint2*)&cs2[wv][lane * 8];
        dst[0] = make_uint2(rr[0], rr[1]);
        dst[1] = make_uint2(rr[2], rr[3]);
        dst[2] = make_uint2(rr[4], rr[5]);
        dst[3] = make_uint2(rr[6], rr[7]);
    }

    // ---- Stage 3: ring-FF 288 -> 10, out = sin(angle) = Y/r (one wave) ----
    // lane = n*6 + g (60 active): output n, features f = g + 6k, k<48.
    // Reduction across the 6-lane group via shfl (no LDS, no barrier).
    {
        float X = 0.f, Y = 0.f;
        const int n = lane / 6;
        const int g = lane - n * 6;
        if (n < 10) {
            #pragma unroll 6
            for (int k = 0; k < 48; ++k) {
                const int f = g + 6 * k;
                unsigned v = cs2[wv][f];
                uint2 wvv = wt[WT_FF + f * 10 + n];
                X = fdot2(v, wvv.x, X);
                Y = fdot2(v, wvv.y, Y);
            }
        }
        // 6-lane group sum: p=v+sh3(v); r=p+sh1(p)+sh2(p)  (valid at g==0)
        float pX = X + __shfl_down(X, 3);
        float pY = Y + __shfl_down(Y, 3);
        float sX = pX + __shfl_down(pX, 1) + __shfl_down(pX, 2);
        float sY = pY + __shfl_down(pY, 1) + __shfl_down(pY, 2);
        if (g == 0 && n < 10) {
            float rinv = rsqrtf(fmaxf(fmaf(sX, sX, sY * sY), 1e-30f));
            out[b * 10 + n] = sY * rinv;
        }
    }
}

extern "C" void kernel_launch(void* const* d_in, const int* in_sizes, int n_in,
                              void* d_out, int out_size, void* d_ws, size_t ws_size,
                              hipStream_t stream) {
    const float* x   = (const float*)d_in[0];
    const float* w1  = (const float*)d_in[1];
    const float* w2  = (const float*)d_in[2];
    const float* ffw = (const float*)d_in[3];
    uint2* wt = (uint2*)d_ws;              // needs 3408*8 = 27264 bytes
    float* o  = (float*)d_out;

    ringnn_setup<<<14, 256, 0, stream>>>(w1, w2, ffw, wt);
    ringnn_main<<<1024, 256, 0, stream>>>(x, wt, o);
}

// Round 8
// 76.975 us; speedup vs baseline: 1.1149x; 1.1149x over previous
//
#include <hip/hip_runtime.h>

// d_ws layout:
//  uint2 wt[3408]: lo = half2(cos, sin) [X-dot], hi = half2(-sin, cos) [Y-dot]
//   [0..15]     conv1 (o*4 + dy*2 + dx)
//   [16..527]   conv2 (o*64 + c*16 + dy*4 + dx)   (kept for reference/debug)
//   [528..3407] ff    (f*10 + n)
//  Then at byte 27264: uint4 Btab[256] — MFMA B-fragments for stage 2:
//   entry e=(c*4+dy)*16+n holds 8 f16 (j=0..7 -> dx=j>>1, comp=j&1), where
//   col n: even -> X column (cos,sin), odd -> Y column (-sin,cos), o=n>>1.
#define WT_W1 0
#define WT_W2 16
#define WT_FF 528
#define WT_B2_BYTES (3408 * 8)

typedef _Float16 h2  __attribute__((ext_vector_type(2)));
typedef _Float16 v8h __attribute__((ext_vector_type(8)));
typedef float    f4  __attribute__((ext_vector_type(4)));

__device__ __forceinline__ float fdot2(unsigned a, unsigned b, float c) {
    return __builtin_amdgcn_fdot2(__builtin_bit_cast(h2, a),
                                  __builtin_bit_cast(h2, b), c, false);
}
__device__ __forceinline__ unsigned packh2(float x, float y) {
    h2 h; h.x = (_Float16)x; h.y = (_Float16)y;
    return __builtin_bit_cast(unsigned, h);
}

__global__ void ringnn_setup(const float* __restrict__ w1,
                             const float* __restrict__ w2,
                             const float* __restrict__ ffw,
                             uint2* __restrict__ wt) {
    int t = blockIdx.x * blockDim.x + threadIdx.x;
    if (t < 3408) {
        float a;
        if (t < 16)        a = w1[t];
        else if (t < 528)  a = w2[t - 16];
        else               a = ffw[t - 528];
        float s, c;
        __sincosf(a, &s, &c);
        uint2 v;
        v.x = packh2(c, s);
        v.y = packh2(-s, c);
        wt[t] = v;
    } else if (t < 3408 + 256) {
        // Build MFMA B-fragment table for stage 2.
        const int e  = t - 3408;
        const int nn = e & 15;
        const int dy = (e >> 4) & 3;
        const int c  = e >> 6;
        const int o  = nn >> 1;
        unsigned d[4];
        #pragma unroll
        for (int dx = 0; dx < 4; ++dx) {
            float a = w2[o * 64 + c * 16 + dy * 4 + dx];
            float s, cc;
            __sincosf(a, &s, &cc);
            d[dx] = (nn & 1) ? packh2(-s, cc) : packh2(cc, s);
        }
        uint4* Bt = (uint4*)((char*)wt + WT_B2_BYTES);
        Bt[e] = make_uint4(d[0], d[1], d[2], d[3]);
    }
}

// 128 threads = 2 waves = 2 images per block; 2048 blocks -> 16 blocks/CU
// = 32 waves/CU (R7's wave-per-image grid only reached 16 waves/CU).
// Stage 1: wave w -> image b0+w (fdot2, weights via wave-uniform s_load).
// Stage 2: MFMA 16x16x32 f16 GEMM over the block's 72 output positions:
//          5 M-tiles, K=128 (4 steps of 32 = one input channel each),
//          N=16 (8 o x {X,Y}). A straight from cs1 LDS; B in 16 VGPRs.
// Stage 3: wave w -> image b0+w, shfl reduction (no LDS).
__global__ __launch_bounds__(128) void ringnn_main(
    const float* __restrict__ x,
    const uint2* __restrict__ wt,
    float* __restrict__ out)
{
    __shared__ unsigned cs1[2][784];        // [img][c*196 + i*14 + j], half2
    __shared__ unsigned cs2[2][288];        // [img][(i*6+j)*8 + o], half2

    const int t    = threadIdx.x;
    const int wv   = t >> 6;                // 0..1
    const int lane = t & 63;
    const int b0   = blockIdx.x * 2;
    const float* xb = x + (b0 + wv) * 784;

    // ---- Stage 1: sincos from global + 2x2/s2 conv, 1->4 ch (one wave) ----
    for (int pos = lane; pos < 196; pos += 64) {
        const int i = pos / 14;
        const int j = pos - i * 14;
        const float* px = xb + (2 * i) * 28 + 2 * j;
        float2 p0 = *(const float2*)(px);
        float2 p1 = *(const float2*)(px + 28);
        float s0, c0, s1, c1, s2, c2, s3, c3;
        __sincosf(p0.x, &s0, &c0);
        __sincosf(p0.y, &s1, &c1);
        __sincosf(p1.x, &s2, &c2);
        __sincosf(p1.y, &s3, &c3);
        unsigned v0 = packh2(c0, s0), v1 = packh2(c1, s1);
        unsigned v2 = packh2(c2, s2), v3 = packh2(c3, s3);
        #pragma unroll
        for (int o = 0; o < 4; ++o) {
            uint2 wa = wt[WT_W1 + o * 4 + 0], wb = wt[WT_W1 + o * 4 + 1];
            uint2 wc = wt[WT_W1 + o * 4 + 2], wd = wt[WT_W1 + o * 4 + 3];
            float X = 0.f, Y = 0.f;
            X = fdot2(v0, wa.x, X); Y = fdot2(v0, wa.y, Y);
            X = fdot2(v1, wb.x, X); Y = fdot2(v1, wb.y, Y);
            X = fdot2(v2, wc.x, X); Y = fdot2(v2, wc.y, Y);
            X = fdot2(v3, wd.x, X); Y = fdot2(v3, wd.y, Y);
            float rinv = rsqrtf(fmaxf(fmaf(X, X, Y * Y), 1e-30f));
            cs1[wv][o * 196 + pos] = packh2(X * rinv, Y * rinv);
        }
    }

    // B-fragments: entry (c*4+quad)*16+n -> index c*64 + lane: coalesced.
    const int n    = lane & 15;
    const int quad = lane >> 4;
    const uint4* Bt = (const uint4*)((const char*)wt + WT_B2_BYTES);
    uint4 bf0 = Bt[lane];
    uint4 bf1 = Bt[64 + lane];
    uint4 bf2 = Bt[128 + lane];
    uint4 bf3 = Bt[192 + lane];

    __syncthreads();

    // ---- Stage 2: MFMA. 72 positions (2 images x 36) = 5 tiles of 16 ----
    const unsigned* c1 = &cs1[0][0];
    for (int tile = wv; tile < 5; tile += 2) {
        const int p  = tile * 16 + n;
        const int pc = (p < 72) ? p : 71;          // clamp pad lanes (tile 4)
        const int im = (pc >= 36) ? 1 : 0;
        const int ps = pc - im * 36;
        const int i  = ps / 6;
        const int j  = ps - i * 6;
        // A row m = lane&15 -> position p; lane quad -> dy; 8 f16 = 16B of
        // cs1 row (dx-contiguous (c,s) pairs) = exactly the A-fragment.
        const unsigned base = (unsigned)(im * 784 + (2 * i + quad) * 14 + 2 * j);
        f4 acc = {0.f, 0.f, 0.f, 0.f};
        #pragma unroll
        for (int c = 0; c < 4; ++c) {
            uint2 lo = *(const uint2*)(c1 + base + c * 196);
            uint2 hi = *(const uint2*)(c1 + base + c * 196 + 2);
            uint4 a4 = make_uint4(lo.x, lo.y, hi.x, hi.y);
            v8h av = __builtin_bit_cast(v8h, a4);
            v8h bv = __builtin_bit_cast(v8h, (c == 0) ? bf0 : (c == 1) ? bf1
                                              : (c == 2) ? bf2 : bf3);
            acc = __builtin_amdgcn_mfma_f32_16x16x32_f16(av, bv, acc, 0, 0, 0);
        }
        // C/D: col = lane&15 = n, rows = quad*4 + r. X in even-n lanes,
        // Y in odd-n lanes -> pair via shfl_xor(1).
        float pr0 = __shfl_xor(acc[0], 1);
        float pr1 = __shfl_xor(acc[1], 1);
        float pr2 = __shfl_xor(acc[2], 1);
        float pr3 = __shfl_xor(acc[3], 1);
        if (!(n & 1)) {
            const int o = n >> 1;
            float Xs[4] = {acc[0], acc[1], acc[2], acc[3]};
            float Ys[4] = {pr0, pr1, pr2, pr3};
            #pragma unroll
            for (int r = 0; r < 4; ++r) {
                const int p2 = tile * 16 + quad * 4 + r;
                if (p2 < 72) {
                    const int im2 = (p2 >= 36) ? 1 : 0;
                    const int ps2 = p2 - im2 * 36;
                    float X = Xs[r], Y = Ys[r];
                    float rinv = rsqrtf(fmaxf(fmaf(X, X, Y * Y), 1e-30f));
                    cs2[im2][ps2 * 8 + o] = packh2(X * rinv, Y * rinv);
                }
            }
        }
    }
    __syncthreads();

    // ---- Stage 3: ring-FF 288 -> 10, out = sin(angle) = Y/r (one wave) ----
    // lane = n3*6 + g (60 active): output n3, features f = g + 6k, k<48.
    {
        float X = 0.f, Y = 0.f;
        const int n3 = lane / 6;
        const int g  = lane - n3 * 6;
        if (n3 < 10) {
            #pragma unroll 6
            for (int k = 0; k < 48; ++k) {
                const int f = g + 6 * k;
                unsigned v = cs2[wv][f];
                uint2 wvv = wt[WT_FF + f * 10 + n3];
                X = fdot2(v, wvv.x, X);
                Y = fdot2(v, wvv.y, Y);
            }
        }
        float pX = X + __shfl_down(X, 3);
        float pY = Y + __shfl_down(Y, 3);
        float sX = pX + __shfl_down(pX, 1) + __shfl_down(pX, 2);
        float sY = pY + __shfl_down(pY, 1) + __shfl_down(pY, 2);
        if (g == 0 && n3 < 10) {
            float rinv = rsqrtf(fmaxf(fmaf(sX, sX, sY * sY), 1e-30f));
            out[(b0 + wv) * 10 + n3] = sY * rinv;
        }
    }
}

extern "C" void kernel_launch(void* const* d_in, const int* in_sizes, int n_in,
                              void* d_out, int out_size, void* d_ws, size_t ws_size,
                              hipStream_t stream) {
    const float* x   = (const float*)d_in[0];
    const float* w1  = (const float*)d_in[1];
    const float* w2  = (const float*)d_in[2];
    const float* ffw = (const float*)d_in[3];
    uint2* wt = (uint2*)d_ws;              // needs 27264 + 4096 = 31360 bytes
    float* o  = (float*)d_out;

    ringnn_setup<<<15, 256, 0, stream>>>(w1, w2, ffw, wt);
    ringnn_main<<<2048, 128, 0, stream>>>(x, wt, o);
}